// Round 6
// baseline (96.759 us; speedup 1.0000x reference)
//
#include <hip/hip_runtime.h>
#include <hip/hip_bf16.h>
#include <stdint.h>

typedef __bf16 bf16x8 __attribute__((ext_vector_type(8)));
typedef float f32x4 __attribute__((ext_vector_type(4)));

__device__ __forceinline__ uint16_t f32_to_bf16_rne(float f) {
    uint32_t u = __float_as_uint(f);
    u += 0x7fffu + ((u >> 16) & 1u);
    return (uint16_t)(u >> 16);
}

// Convert two fp32 arrays to bf16 (RNE) in one grid-stride kernel.
__global__ void cvt2_kernel(const float* __restrict__ a, long na4,
                            const float* __restrict__ b, long nb4,
                            uint16_t* __restrict__ oa, uint16_t* __restrict__ ob) {
    long i = (long)blockIdx.x * blockDim.x + threadIdx.x;
    const long stride = (long)gridDim.x * blockDim.x;
    const long tot = na4 + nb4;
    for (; i < tot; i += stride) {
        const float4* src; ushort4* dst; long j;
        if (i < na4) { src = (const float4*)a; dst = (ushort4*)oa; j = i; }
        else         { src = (const float4*)b; dst = (ushort4*)ob; j = i - na4; }
        float4 f = src[j];
        ushort4 o;
        o.x = f32_to_bf16_rne(f.x);
        o.y = f32_to_bf16_rne(f.y);
        o.z = f32_to_bf16_rne(f.z);
        o.w = f32_to_bf16_rne(f.w);
        dst[j] = o;
    }
}

// ---------------------------------------------------------------------------
// Big-wave-tile phase-lagged GEMM: BM=256, BN=128, BK=32, 256 threads
// (4 waves, 2M x 2N), per-wave 128x64 output (acc 8x4 f32x4 = 128 VGPR).
// Ring of 3 LDS regions x 24 KiB = 72 KiB  ->  2 blocks/CU, and the 2
// waves/SIMD come from INDEPENDENT blocks (cross-block overlap fills
// barrier/vmcnt stalls).
// Region layout: A[256r][32k] (16 KiB) + B[128r][32k] (8 KiB at +16384).
// 128-B super-rows hold 2 tile-rows; 16-B chunk c of super-row sr stored at
// slot c ^ (sr&7)  ->  fragment b128 reads land 2 lanes/bank (free).
// Phase p: barrier; READ12(region p) -> set S_p; STAGE6(region p+2);
// MFMA32(S_{p-1}); vmcnt(6) (drains region p+1 -> race-free publication).
// ---------------------------------------------------------------------------

#define GLD(gp, lp) __builtin_amdgcn_global_load_lds(                           \
    (const __attribute__((address_space(1))) uint32_t*)(gp),                    \
    (__attribute__((address_space(3))) uint32_t*)(void*)(lp), 16, 0, 0)

// Stage one K32 region: 4 A-issues + 2 B-issues (6 vmcnt items/thread).
#define STAGE6(KB, BS) do {                                                     \
    GLD(Abyte + offA0 + (KB), lds + (BS) + t16);                                \
    GLD(Abyte + offA1 + (KB), lds + (BS) + 4096  + t16);                        \
    GLD(Abyte + offA2 + (KB), lds + (BS) + 8192  + t16);                        \
    GLD(Abyte + offA3 + (KB), lds + (BS) + 12288 + t16);                        \
    GLD(Bbyte + offB0 + (KB), lds + (BS) + 16384 + t16);                        \
    GLD(Bbyte + offB1 + (KB), lds + (BS) + 20480 + t16);                        \
} while (0)

// Read 8 A-frags + 4 B-frags of one region (region base = byte offset RB).
#define READ12(P, RB) do {                                                      \
    const uint8_t* rb_ = lds + (RB);                                            \
    P##a0 = *(const bf16x8*)(rb_ + aof0);                                       \
    P##a1 = *(const bf16x8*)(rb_ + aof1);                                       \
    P##a2 = *(const bf16x8*)(rb_ + aof2);                                       \
    P##a3 = *(const bf16x8*)(rb_ + aof3);                                       \
    P##a4 = *(const bf16x8*)(rb_ + aof4);                                       \
    P##a5 = *(const bf16x8*)(rb_ + aof5);                                       \
    P##a6 = *(const bf16x8*)(rb_ + aof6);                                       \
    P##a7 = *(const bf16x8*)(rb_ + aof7);                                       \
    P##b0 = *(const bf16x8*)(rb_ + bof0);                                       \
    P##b1 = *(const bf16x8*)(rb_ + bof1);                                       \
    P##b2 = *(const bf16x8*)(rb_ + bof2);                                       \
    P##b3 = *(const bf16x8*)(rb_ + bof3);                                       \
} while (0)

#define MROW(P, AR, mi) do {                                                    \
    acc[mi][0] = __builtin_amdgcn_mfma_f32_16x16x32_bf16(P##AR, P##b0, acc[mi][0], 0, 0, 0); \
    acc[mi][1] = __builtin_amdgcn_mfma_f32_16x16x32_bf16(P##AR, P##b1, acc[mi][1], 0, 0, 0); \
    acc[mi][2] = __builtin_amdgcn_mfma_f32_16x16x32_bf16(P##AR, P##b2, acc[mi][2], 0, 0, 0); \
    acc[mi][3] = __builtin_amdgcn_mfma_f32_16x16x32_bf16(P##AR, P##b3, acc[mi][3], 0, 0, 0); \
} while (0)

#define MFMA32(P) do {                                                          \
    MROW(P, a0, 0); MROW(P, a1, 1); MROW(P, a2, 2); MROW(P, a3, 3);             \
    MROW(P, a4, 4); MROW(P, a5, 5); MROW(P, a6, 6); MROW(P, a7, 7);             \
} while (0)

#define ROT3() do { uint32_t t_ = r0; r0 = r1; r1 = r2; r2 = t_; } while (0)

// Full phase: read region p into set R, MFMA set M (read last phase),
// stage region p+2, counted vmcnt publishes region p+1 for the next barrier.
#define PHASEF(R, M, STG, VM) do {                                              \
    __builtin_amdgcn_s_barrier();                                               \
    __builtin_amdgcn_sched_barrier(0);                                          \
    READ12(R, r0);                                                              \
    STG;                                                                        \
    __builtin_amdgcn_s_setprio(1); MFMA32(M); __builtin_amdgcn_s_setprio(0);    \
    VM;                                                                         \
    ROT3(); kk2 += 64;                                                          \
} while (0)

__global__ __launch_bounds__(256, 2) void gemm_bw_bf16(
    const uint16_t* __restrict__ A,   // M x K bf16 (x)
    const uint16_t* __restrict__ B,   // N x K bf16 (weight)
    const float* __restrict__ bias,
    float* __restrict__ C, int M, int N, int K)
{
    extern __shared__ __align__(16) uint8_t lds[];
    const int tid  = threadIdx.x;
    const int lane = tid & 63;
    const int wave = tid >> 6;
    const int wr = wave >> 1;   // 0..1 (M, 128-row halves)
    const int wc = wave & 1;    // 0..1 (N, 64-col halves)

    // Bijective XCD-aware swizzle.
    const int nwg = gridDim.x;
    int swz;
    {
        const int q = nwg >> 3, r = nwg & 7;
        const int xcd = blockIdx.x & 7, k = blockIdx.x >> 3;
        swz = (xcd < r ? xcd * (q + 1) : r * (q + 1) + (xcd - r) * q) + k;
    }
    const int MB = M >> 8;
    const int brow = swz % MB;
    const int bcol = swz / MB;

    const uint8_t* Abyte = (const uint8_t*)A;
    const uint8_t* Bbyte = (const uint8_t*)B;
    const int t16 = tid * 16;

    // Staging source offsets (bytes), inverse of the LDS super-row swizzle.
    // LDS chunk ci (16 B): sr = ci>>3, slot = ci&7, global chunk c = slot^(sr&7),
    // tile-row r = 2*sr + (c>>2), k-chunk kc = c&3.
    uint32_t offA0, offA1, offA2, offA3, offB0, offB1;
    {
        int ci, sr, c;
        ci = 0 * 256 + tid; sr = ci >> 3; c = (ci & 7) ^ (sr & 7);
        offA0 = (uint32_t)(brow * 256 + sr * 2 + (c >> 2)) * (uint32_t)(K * 2) + (c & 3) * 16;
        ci = 1 * 256 + tid; sr = ci >> 3; c = (ci & 7) ^ (sr & 7);
        offA1 = (uint32_t)(brow * 256 + sr * 2 + (c >> 2)) * (uint32_t)(K * 2) + (c & 3) * 16;
        ci = 2 * 256 + tid; sr = ci >> 3; c = (ci & 7) ^ (sr & 7);
        offA2 = (uint32_t)(brow * 256 + sr * 2 + (c >> 2)) * (uint32_t)(K * 2) + (c & 3) * 16;
        ci = 3 * 256 + tid; sr = ci >> 3; c = (ci & 7) ^ (sr & 7);
        offA3 = (uint32_t)(brow * 256 + sr * 2 + (c >> 2)) * (uint32_t)(K * 2) + (c & 3) * 16;
        ci = 0 * 256 + tid; sr = ci >> 3; c = (ci & 7) ^ (sr & 7);
        offB0 = (uint32_t)(bcol * 128 + sr * 2 + (c >> 2)) * (uint32_t)(K * 2) + (c & 3) * 16;
        ci = 1 * 256 + tid; sr = ci >> 3; c = (ci & 7) ^ (sr & 7);
        offB1 = (uint32_t)(bcol * 128 + sr * 2 + (c >> 2)) * (uint32_t)(K * 2) + (c & 3) * 16;
    }

    // Fragment read offsets (region-relative bytes), swizzled.
    // Lane (lm + 16 g) reads row (rowbase+lm), k-chunk g:
    //   sr = r>>1, c = (r&1)*4 + g, byte = sr*128 + (c ^ (sr&7))*16.
    const int lm = lane & 15;
    const int g  = lane >> 4;
    int aof0, aof1, aof2, aof3, aof4, aof5, aof6, aof7, bof0, bof1, bof2, bof3;
    {
        int r, sr, c;
#define FOFF(DEST, RB, BASE) \
        r = (RB) + lm; sr = r >> 1; c = (r & 1) * 4 + g;                        \
        DEST = (BASE) + sr * 128 + ((c ^ (sr & 7)) << 4)
        FOFF(aof0, wr * 128 +   0, 0);
        FOFF(aof1, wr * 128 +  16, 0);
        FOFF(aof2, wr * 128 +  32, 0);
        FOFF(aof3, wr * 128 +  48, 0);
        FOFF(aof4, wr * 128 +  64, 0);
        FOFF(aof5, wr * 128 +  80, 0);
        FOFF(aof6, wr * 128 +  96, 0);
        FOFF(aof7, wr * 128 + 112, 0);
        FOFF(bof0, wc * 64 +   0, 16384);
        FOFF(bof1, wc * 64 +  16, 16384);
        FOFF(bof2, wc * 64 +  32, 16384);
        FOFF(bof3, wc * 64 +  48, 16384);
#undef FOFF
    }

    f32x4 acc[8][4];
#pragma unroll
    for (int m = 0; m < 8; ++m)
#pragma unroll
        for (int n = 0; n < 4; ++n)
            acc[m][n] = (f32x4){0.f, 0.f, 0.f, 0.f};

    // Fragment register sets (E/O alternate by phase parity).
    bf16x8 Ea0, Ea1, Ea2, Ea3, Ea4, Ea5, Ea6, Ea7, Eb0, Eb1, Eb2, Eb3;
    bf16x8 Oa0, Oa1, Oa2, Oa3, Oa4, Oa5, Oa6, Oa7, Ob0, Ob1, Ob2, Ob3;

    const int nph = K >> 5;          // K32 phases; launcher: even, >= 4
    uint32_t r0 = 0, r1 = 24576, r2 = 49152;
    uint32_t kk2 = 128;              // byte k-offset staged by current phase ((p+2)*64)

    // Prologue: stage regions 0,1; publish region 0.
    STAGE6(0, r0);
    STAGE6(64, r1);
    asm volatile("s_waitcnt vmcnt(6)" ::: "memory");

    // Phase 0 (reads E, no MFMA, stages region 2).
    __builtin_amdgcn_s_barrier();
    __builtin_amdgcn_sched_barrier(0);
    READ12(E, r0);
    STAGE6(kk2, r2);
    asm volatile("s_waitcnt vmcnt(6)" ::: "memory");
    ROT3(); kk2 += 64;

    // Full phases 1 .. nph-3 (each stages region p+2, publishes region p+1).
    for (int p = 1; p + 1 <= nph - 4; p += 2) {
        PHASEF(O, E, STAGE6(kk2, r2), asm volatile("s_waitcnt vmcnt(6)" ::: "memory"));
        PHASEF(E, O, STAGE6(kk2, r2), asm volatile("s_waitcnt vmcnt(6)" ::: "memory"));
    }
    // Phase nph-3 (odd parity): last staged region (nph-1).
    PHASEF(O, E, STAGE6(kk2, r2), asm volatile("s_waitcnt vmcnt(6)" ::: "memory"));
    // Phase nph-2 (even): no stage; drain everything (publishes region nph-1).
    PHASEF(E, O, (void)0, asm volatile("s_waitcnt vmcnt(0)" ::: "memory"));
    // Phase nph-1 (odd): final region.
    PHASEF(O, E, (void)0, (void)0);
    // Trailing: consume the last-read set.
    MFMA32(O);

    // Epilogue: D mapping col = lane&15 (N), row = (lane>>4)*4 + t (M).
    const int crow0 = brow * 256 + wr * 128 + (lane >> 4) * 4;
    const int ccol0 = bcol * 128 + wc * 64 + lm;
#pragma unroll
    for (int nf = 0; nf < 4; ++nf) {
        const int col = ccol0 + nf * 16;
        const float bv = bias[col];
#pragma unroll
        for (int mf = 0; mf < 8; ++mf) {
#pragma unroll
            for (int tt = 0; tt < 4; ++tt) {
                const int row = crow0 + mf * 16 + tt;
                C[(size_t)row * N + col] = acc[mf][nf][tt] + bv;
            }
        }
    }
}

// ---------------------------------------------------------------------------
// Fallback 1: verified m97-structure 128x128 kernel.
// ---------------------------------------------------------------------------
__global__ __launch_bounds__(256) void gemm_bf16_kernel(
    const uint16_t* __restrict__ A,
    const uint16_t* __restrict__ B,
    const float* __restrict__ bias,
    float* __restrict__ C, int M, int N, int K)
{
    __shared__ __align__(16) uint16_t Alds[128 * 32];
    __shared__ __align__(16) uint16_t Blds[128 * 32];

    const int tid  = threadIdx.x;
    const int lane = tid & 63;
    const int wave = tid >> 6;
    const int wm = wave >> 1, wn = wave & 1;

    const int MB = M >> 7;
    const int brow = blockIdx.x % MB;
    const int bcol = blockIdx.x / MB;

    const int off0 = wave * 1024 + lane * 16;
    const int row0 = off0 >> 6;
    const int colb = off0 & 63;

    const uint8_t* gA0 = (const uint8_t*)A + ((size_t)(brow * 128 + row0) * K) * 2 + colb;
    const uint8_t* gA1 = gA0 + (size_t)64 * K * 2;
    const uint8_t* gB0 = (const uint8_t*)B + ((size_t)(bcol * 128 + row0) * K) * 2 + colb;
    const uint8_t* gB1 = gB0 + (size_t)64 * K * 2;

    uint32_t* lA0 = (uint32_t*)((uint8_t*)Alds + off0);
    uint32_t* lA1 = (uint32_t*)((uint8_t*)Alds + off0 + 4096);
    uint32_t* lB0 = (uint32_t*)((uint8_t*)Blds + off0);
    uint32_t* lB1 = (uint32_t*)((uint8_t*)Blds + off0 + 4096);

#define STAGE_OLD() do {                                                                   \
    __builtin_amdgcn_global_load_lds((const __attribute__((address_space(1))) uint32_t*)gA0, \
                                     (__attribute__((address_space(3))) uint32_t*)lA0, 16, 0, 0); \
    __builtin_amdgcn_global_load_lds((const __attribute__((address_space(1))) uint32_t*)gA1, \
                                     (__attribute__((address_space(3))) uint32_t*)lA1, 16, 0, 0); \
    __builtin_amdgcn_global_load_lds((const __attribute__((address_space(1))) uint32_t*)gB0, \
                                     (__attribute__((address_space(3))) uint32_t*)lB0, 16, 0, 0); \
    __builtin_amdgcn_global_load_lds((const __attribute__((address_space(1))) uint32_t*)gB1, \
                                     (__attribute__((address_space(3))) uint32_t*)lB1, 16, 0, 0); \
    gA0 += 64; gA1 += 64; gB0 += 64; gB1 += 64;                                            \
} while (0)

    f32x4 acc[4][4];
#pragma unroll
    for (int mf = 0; mf < 4; ++mf)
#pragma unroll
        for (int nf = 0; nf < 4; ++nf)
            acc[mf][nf] = (f32x4){0.f, 0.f, 0.f, 0.f};

    const int nk = K >> 5;
    STAGE_OLD();

    const int arow = wm * 64 + (lane & 15);
    const int brw  = wn * 64 + (lane & 15);
    const int ke   = (lane >> 4) * 8;

    for (int kt = 0; kt < nk; ++kt) {
        __syncthreads();
        bf16x8 af[4], bfr[4];
#pragma unroll
        for (int mf = 0; mf < 4; ++mf)
            af[mf] = *(const bf16x8*)(&Alds[(arow + mf * 16) * 32 + ke]);
#pragma unroll
        for (int nf = 0; nf < 4; ++nf)
            bfr[nf] = *(const bf16x8*)(&Blds[(brw + nf * 16) * 32 + ke]);
        __syncthreads();
        if (kt + 1 < nk) STAGE_OLD();
#pragma unroll
        for (int mf = 0; mf < 4; ++mf)
#pragma unroll
            for (int nf = 0; nf < 4; ++nf)
                acc[mf][nf] = __builtin_amdgcn_mfma_f32_16x16x32_bf16(
                    af[mf], bfr[nf], acc[mf][nf], 0, 0, 0);
    }
#undef STAGE_OLD

    const int crow0 = brow * 128 + wm * 64 + (lane >> 4) * 4;
    const int ccol0 = bcol * 128 + wn * 64 + (lane & 15);
#pragma unroll
    for (int nf = 0; nf < 4; ++nf) {
        const int col = ccol0 + nf * 16;
        const float bv = bias[col];
#pragma unroll
        for (int mf = 0; mf < 4; ++mf) {
#pragma unroll
            for (int t = 0; t < 4; ++t) {
                const int row = crow0 + mf * 16 + t;
                C[(size_t)row * N + col] = acc[mf][nf][t] + bv;
            }
        }
    }
}

// Fallback 2: fp32 vector GEMM, one block per row.
__global__ void gemm_fallback(const float* __restrict__ x, const float* __restrict__ w,
                              const float* __restrict__ bias, float* __restrict__ out,
                              int M, int N, int K) {
    extern __shared__ float xs[];
    const int b = blockIdx.x;
    for (int k = threadIdx.x; k < K; k += blockDim.x) xs[k] = x[(size_t)b * K + k];
    __syncthreads();
    for (int j = threadIdx.x; j < N; j += blockDim.x) {
        const float* wr = w + (size_t)j * K;
        float s = 0.f;
        for (int k = 0; k < K; ++k) s += xs[k] * wr[k];
        out[(size_t)b * N + j] = s + bias[j];
    }
}

extern "C" void kernel_launch(void* const* d_in, const int* in_sizes, int n_in,
                              void* d_out, int out_size, void* d_ws, size_t ws_size,
                              hipStream_t stream) {
    const float* x    = (const float*)d_in[0];
    const float* w    = (const float*)d_in[1];
    const float* bias = (const float*)d_in[2];
    float* out = (float*)d_out;

    const int N = in_sizes[2];
    const int K = in_sizes[1] / N;
    const int M = in_sizes[0] / K;

    const size_t need = ((size_t)M * K + (size_t)N * K) * 2;
    const bool ws_ok = ws_size >= need;

    if ((M % 256 == 0) && (N % 128 == 0) && (K % 64 == 0) && (K >= 128) && ws_ok) {
        uint16_t* xb = (uint16_t*)d_ws;
        uint16_t* wb = xb + (size_t)M * K;
        const long na4 = (long)M * K / 4, nb4 = (long)N * K / 4;
        cvt2_kernel<<<2048, 256, 0, stream>>>(x, na4, w, nb4, xb, wb);
        (void)hipFuncSetAttribute((const void*)gemm_bw_bf16,
                                  hipFuncAttributeMaxDynamicSharedMemorySize, 73728);
        dim3 grid((M / 256) * (N / 128));
        gemm_bw_bf16<<<grid, 256, 73728, stream>>>(xb, wb, bias, out, M, N, K);
    } else if ((M % 128 == 0) && (N % 128 == 0) && (K % 32 == 0) && ws_ok) {
        uint16_t* xb = (uint16_t*)d_ws;
        uint16_t* wb = xb + (size_t)M * K;
        const long na4 = (long)M * K / 4, nb4 = (long)N * K / 4;
        cvt2_kernel<<<2048, 256, 0, stream>>>(x, na4, w, nb4, xb, wb);
        dim3 grid((M / 128) * (N / 128));
        gemm_bf16_kernel<<<grid, 256, 0, stream>>>(xb, wb, bias, out, M, N, K);
    } else {
        gemm_fallback<<<M, 256, (size_t)K * 4, stream>>>(x, w, bias, out, M, N, K);
    }
}